// Round 7
// baseline (110.627 us; speedup 1.0000x reference)
//
#include <hip/hip_runtime.h>

// DropGCN: out = relu( mean_r( diag(k_r) A diag(k_r) X ) @ W^T + b )
//  == Y[8192,160] = A @ Xm   (Xm[:, r*32+d] = k_r .* X[:,d], bf16)
//  then per-row masked mean over the 5 replica slices, @W^T, +b, relu.
//
// Round 7: r4 skeleton (best, 97.4 us: 256-row blocks, 8 waves x 2 m-tiles,
// KSPLIT=8, double-buffered LDS slice, reg-staged, 1 __syncthreads/step)
// + A-fetch BATCHED over 2 K-steps: each A row is read as one 256 B
// contiguous burst (4 kg-lanes x 4 dwordx4 issued together) instead of
// 128 B per step -> doubles DRAM row-activation utilization (the r6
// post-mortem's computed bottleneck: 268 MB stream was running at ~3.2 TB/s
// because each step pulled only 128 B per activated row).
// prep carried from r6 (verified): merged mask-norm + PRE-SWIZZLED XmG, so
// gemm stages chunks LINEARLY into LDS and reads swizzled (rule #21).

#define N_NODES   8192
#define NSLICES   256          // 8192/32 K-slices
#define NCOLS     160          // 5 replicas * 32 dims
#define SLICE_US  5120         // ushorts per K-slice image (160*32)
#define MASK_WS   65536        // ws bytes reserved for normalized mask
#define KSPLIT    8
#define STEPS     (NSLICES / KSPLIT)   // 32 K-steps per block

typedef __attribute__((ext_vector_type(4))) float f32x4;
typedef __attribute__((ext_vector_type(8))) short bf16x8;

__device__ __forceinline__ unsigned short f2bf(float f) {
  // round-to-nearest-even f32 -> bf16 bits
  unsigned int u = __builtin_bit_cast(unsigned int, f);
  return (unsigned short)((u + 0x7FFFu + ((u >> 16) & 1u)) >> 16);
}

__device__ __forceinline__ unsigned pack_bf(float lo, float hi) {
  // two f32 -> packed bf16 pair (round-to-nearest ties-up; verified r3-r6)
  unsigned u0 = __builtin_bit_cast(unsigned, lo) + 0x8000u;
  unsigned u1 = __builtin_bit_cast(unsigned, hi) + 0x8000u;
  return (u1 & 0xFFFF0000u) | (u0 >> 16);
}

// ---------------------------------------------------------------------------
// prep (verified r6): block s handles K-slice s. Coalesced X read -> LDS
// transpose; mask dtype detect + normalize; XmG written PRE-SWIZZLED: chunk
// position c (16 B) of slice s holds (n = c>>2, kg = (c&3) ^ ((n>>1)&3)).
// Linear staging of the slice into LDS then matches the swizzled-read map.
// ---------------------------------------------------------------------------
__global__ __launch_bounds__(256) void prep_kernel(
    const float* __restrict__ X, const void* __restrict__ raw,
    unsigned char* __restrict__ mk, unsigned short* __restrict__ XmG) {
  __shared__ float xt[32 * 33];   // [kk][d], pad 33
  __shared__ float mf[160];       // [r][kk] 0/1
  __shared__ int mode32s;
  const int tid = threadIdx.x;
  const int s = blockIdx.x;

  if (tid == 0) {
    const unsigned* wrd = (const unsigned*)raw;
    int ok = 1;
    for (int i = 0; i < 64; ++i) {
      unsigned v = wrd[i];
      if (!(v <= 1u || v == 0x3F800000u)) { ok = 0; break; }
    }
    mode32s = ok;
  }
  f32x4 xv = *(const f32x4*)(X + (size_t)s * 1024 + tid * 4);
  __syncthreads();
  const int mode32 = mode32s;
#pragma unroll
  for (int q = 0; q < 4; ++q) {
    int e = tid * 4 + q;                 // e = jj*32 + d
    xt[(e >> 5) * 33 + (e & 31)] = xv[q];
  }
  if (tid < 160) {
    int r = tid >> 5, jj = tid & 31;
    int gi = r * N_NODES + s * 32 + jj;
    unsigned char kv = mode32 ? (unsigned char)(((const unsigned*)raw)[gi] != 0u)
                              : (unsigned char)(((const unsigned char*)raw)[gi] != 0);
    mk[gi] = kv;
    mf[tid] = kv ? 1.0f : 0.0f;
  }
  __syncthreads();

  unsigned short* outp = XmG + (size_t)s * SLICE_US;
  for (int c = tid; c < 640; c += 256) {
    int n = c >> 2;
    int kg = (c & 3) ^ ((n >> 1) & 3);   // PRE-SWIZZLE (involution)
    int r = n >> 5, d = n & 31;
    union { bf16x8 v; unsigned short us[8]; } o;
#pragma unroll
    for (int e = 0; e < 8; ++e) {
      int kk = kg * 8 + e;
      o.us[e] = f2bf(mf[r * 32 + kk] * xt[kk * 33 + d]);
    }
    *(bf16x8*)(outp + c * 8) = o.v;
  }
}

// ---------------------------------------------------------------------------
// gemm: block = 8 waves x 32 rows = 256 rows, all 160 cols, K-range 1024.
// grid (32, 8) = 256 blocks = 1/CU. Double-buffered 10 KB slice, reg-staged
// (LINEAR writes; XmG pre-swizzled), 1 __syncthreads/step (r4-verified).
// A pipeline: 2 banks (bkA/bkB, static names), each bank = 2 K-steps of A
// = per lane 8 f32x4 covering, per row, one contiguous 256 B burst.
// Bank reloaded right after its packs, 2 steps of latency cover.
// Verified D map: acc[nt][jj] = Y[base_m + n0][nt*16 + kg*4 + jj].
// Fused replica mask-mean epilogue -> partZ[sy][m][d] f32.
// ---------------------------------------------------------------------------
__global__ __launch_bounds__(512, 2) void gemm_kernel(
    const float* __restrict__ A, const unsigned short* __restrict__ XmG,
    const unsigned char* __restrict__ mk, float* __restrict__ partZ) {
  __shared__ __align__(16) unsigned short xm[2][SLICE_US];   // 20 KB

  const int tid  = threadIdx.x;
  const int lane = tid & 63;
  const int w    = tid >> 6;        // wave 0..7
  const int n0   = lane & 15;
  const int kg   = lane >> 4;       // k-group 0..3 (8 elems each)
  const int sy   = blockIdx.y;      // k-split 0..7
  const int s_base = sy * STEPS;
  const int base_m = blockIdx.x * 256 + w * 32;   // wave owns 32 rows

  const float* aptr0 =
      A + (size_t)(base_m + n0) * N_NODES + s_base * 32 + kg * 8;
  const float* aptr1 = aptr0 + (size_t)16 * N_NODES;

  // staging: 640 chunks over 512 threads (tid<128 take a second chunk);
  // XmG pre-swizzled -> LDS writes are LINEAR (chunk c -> ushort c*8)
  const unsigned short* xsrc = XmG + (size_t)s_base * SLICE_US;
  const int c0 = tid;
  const int c1 = tid + 512;
  const bool has2 = (tid < 128);

  // fragment read base (swizzled slot; consistent across nt since 16|nt*16)
  const unsigned short* frag0 =
      &xm[0][0] + n0 * 32 + ((kg ^ ((n0 >> 1) & 3)) << 3);

  f32x4 acc0[10], acc1[10];
#pragma unroll
  for (int i = 0; i < 10; ++i) {
    acc0[i] = (f32x4){0.f, 0.f, 0.f, 0.f};
    acc1[i] = (f32x4){0.f, 0.f, 0.f, 0.f};
  }

  // A bank: 2 K-steps, per row a contiguous 256 B burst across kg lanes.
  // bk[0..1]=tile0 step t0, bk[2..3]=tile0 step t0+1, bk[4..7] same tile1.
#define LOAD_BANK(bk, t0)                                                      \
  {                                                                            \
    const float* q0_ = aptr0 + (size_t)(t0)*32;                                \
    const float* q1_ = aptr1 + (size_t)(t0)*32;                                \
    bk[0] = __builtin_nontemporal_load((const f32x4*)q0_);                     \
    bk[1] = __builtin_nontemporal_load((const f32x4*)(q0_ + 4));               \
    bk[2] = __builtin_nontemporal_load((const f32x4*)(q0_ + 32));              \
    bk[3] = __builtin_nontemporal_load((const f32x4*)(q0_ + 36));              \
    bk[4] = __builtin_nontemporal_load((const f32x4*)q1_);                     \
    bk[5] = __builtin_nontemporal_load((const f32x4*)(q1_ + 4));               \
    bk[6] = __builtin_nontemporal_load((const f32x4*)(q1_ + 32));              \
    bk[7] = __builtin_nontemporal_load((const f32x4*)(q1_ + 36));              \
  }

  // one K-step: stage slice t+1 (write), load slice t+2 (regs), frags+MFMA,
  // barrier. b0_/b1_ are prepacked bf16 fragments for tiles 0/1.
#define KSTEP_MFMA(t, b0_, b1_)                                                \
  {                                                                            \
    if ((t) + 1 < STEPS) {                                                     \
      unsigned short* dst_ = &xm[cur ^ 1][0];                                  \
      *(bf16x8*)(dst_ + c0 * 8) = sa;                                          \
      if (has2) *(bf16x8*)(dst_ + c1 * 8) = sb2;                               \
    }                                                                          \
    if ((t) + 2 < STEPS) {                                                     \
      const unsigned short* s2_ = xsrc + (size_t)((t) + 2) * SLICE_US;         \
      sa = *(const bf16x8*)(s2_ + c0 * 8);                                     \
      if (has2) sb2 = *(const bf16x8*)(s2_ + c1 * 8);                          \
    }                                                                          \
    const unsigned short* fb_ = frag0 + cur * SLICE_US;                        \
    _Pragma("unroll") for (int nt = 0; nt < 10; ++nt) {                        \
      bf16x8 xf_ = *(const bf16x8*)(fb_ + nt * 512);                           \
      acc0[nt] =                                                               \
          __builtin_amdgcn_mfma_f32_16x16x32_bf16(xf_, b0_.v, acc0[nt], 0, 0, 0);\
      acc1[nt] =                                                               \
          __builtin_amdgcn_mfma_f32_16x16x32_bf16(xf_, b1_.v, acc1[nt], 0, 0, 0);\
    }                                                                          \
    __syncthreads();                                                           \
    cur ^= 1;                                                                  \
  }

  // super-step: pack both K-steps' fragments from bank, reload bank (t0+4),
  // then run the two K-steps.
#define SUPER(t0, bk)                                                          \
  {                                                                            \
    union { bf16x8 v; unsigned u[4]; } p00, p01, p10, p11;                     \
    p00.u[0] = pack_bf(bk[0][0], bk[0][1]);                                    \
    p00.u[1] = pack_bf(bk[0][2], bk[0][3]);                                    \
    p00.u[2] = pack_bf(bk[1][0], bk[1][1]);                                    \
    p00.u[3] = pack_bf(bk[1][2], bk[1][3]);                                    \
    p01.u[0] = pack_bf(bk[4][0], bk[4][1]);                                    \
    p01.u[1] = pack_bf(bk[4][2], bk[4][3]);                                    \
    p01.u[2] = pack_bf(bk[5][0], bk[5][1]);                                    \
    p01.u[3] = pack_bf(bk[5][2], bk[5][3]);                                    \
    p10.u[0] = pack_bf(bk[2][0], bk[2][1]);                                    \
    p10.u[1] = pack_bf(bk[2][2], bk[2][3]);                                    \
    p10.u[2] = pack_bf(bk[3][0], bk[3][1]);                                    \
    p10.u[3] = pack_bf(bk[3][2], bk[3][3]);                                    \
    p11.u[0] = pack_bf(bk[6][0], bk[6][1]);                                    \
    p11.u[1] = pack_bf(bk[6][2], bk[6][3]);                                    \
    p11.u[2] = pack_bf(bk[7][0], bk[7][1]);                                    \
    p11.u[3] = pack_bf(bk[7][2], bk[7][3]);                                    \
    LOAD_BANK(bk, ((t0) + 4 < STEPS) ? (t0) + 4 : (t0));                       \
    KSTEP_MFMA((t0), p00, p01);                                                \
    KSTEP_MFMA((t0) + 1, p10, p11);                                            \
  }

  // prologue: slice0 -> LDS buf0 (linear), slice1 -> regs; banks for steps
  // 0-1 and 2-3.
  bf16x8 sa = *(const bf16x8*)(xsrc + c0 * 8);
  bf16x8 sb2 = sa;
  if (has2) sb2 = *(const bf16x8*)(xsrc + c1 * 8);
  f32x4 bkA[8], bkB[8];
  LOAD_BANK(bkA, 0);
  LOAD_BANK(bkB, 2);
  *(bf16x8*)(&xm[0][c0 * 8]) = sa;
  if (has2) *(bf16x8*)(&xm[0][c1 * 8]) = sb2;
  sa = *(const bf16x8*)(xsrc + SLICE_US + c0 * 8);
  if (has2) sb2 = *(const bf16x8*)(xsrc + SLICE_US + c1 * 8);
  __syncthreads();

  int cur = 0;
  for (int t4 = 0; t4 < STEPS; t4 += 4) {
    SUPER(t4, bkA);
    SUPER(t4 + 2, bkB);
  }

  // fused replica mask-mean epilogue:
  // acc[2r][jj]  = Y[m][32r + kg*4+jj]       (d = kg*4+jj)
  // acc[2r+1][jj]= Y[m][32r + 16 + kg*4+jj]  (d = kg*4+jj+16)
  const int m0g = base_m + n0;
  const int m1g = m0g + 16;
  float w0[5], w1[5];
#pragma unroll
  for (int t = 0; t < 5; ++t) {
    w0[t] = mk[t * N_NODES + m0g] ? 0.2f : 0.0f;
    w1[t] = mk[t * N_NODES + m1g] ? 0.2f : 0.0f;
  }
  f32x4 zA0 = (f32x4){0.f, 0.f, 0.f, 0.f}, zB0 = zA0, zA1 = zA0, zB1 = zA0;
#pragma unroll
  for (int t = 0; t < 5; ++t) {
    zA0 += w0[t] * acc0[2 * t];
    zB0 += w0[t] * acc0[2 * t + 1];
    zA1 += w1[t] * acc1[2 * t];
    zB1 += w1[t] * acc1[2 * t + 1];
  }
  float* p0 = partZ + ((size_t)sy * N_NODES + m0g) * 32 + kg * 4;
  *(f32x4*)(p0)      = zA0;
  *(f32x4*)(p0 + 16) = zB0;
  float* p1 = partZ + ((size_t)sy * N_NODES + m1g) * 32 + kg * 4;
  *(f32x4*)(p1)      = zA1;
  *(f32x4*)(p1 + 16) = zB1;
}

// ---------------------------------------------------------------------------
// epi: z[m][d] = sum_s partZ[s][m][d];  out[m][o] = relu(b[o] + z . W[o])
// ---------------------------------------------------------------------------
__global__ __launch_bounds__(64) void epi_kernel(
    const float* __restrict__ partZ, const float* __restrict__ W,
    const float* __restrict__ bias, float* __restrict__ out) {
  __shared__ float sW[1024];
  __shared__ float sb[32];
  const int tid = threadIdx.x;
  for (int i = tid; i < 1024; i += 64) sW[i] = W[i];
  if (tid < 32) sb[tid] = bias[tid];
  __syncthreads();

  const int m = blockIdx.x * 64 + tid;
  float zz[32];
#pragma unroll
  for (int i = 0; i < 32; ++i) zz[i] = 0.f;
  const float* p = partZ + (size_t)m * 32;
  for (int s = 0; s < KSPLIT; ++s) {
    const float* ps = p + (size_t)s * N_NODES * 32;
#pragma unroll
    for (int i = 0; i < 8; ++i) {
      f32x4 v = *(const f32x4*)(ps + i * 4);
      zz[4 * i + 0] += v[0]; zz[4 * i + 1] += v[1];
      zz[4 * i + 2] += v[2]; zz[4 * i + 3] += v[3];
    }
  }
#pragma unroll
  for (int o = 0; o < 32; o += 4) {
    f32x4 r;
#pragma unroll
    for (int q = 0; q < 4; ++q) {
      float a = sb[o + q];
#pragma unroll
      for (int d = 0; d < 32; ++d) a = fmaf(zz[d], sW[(o + q) * 32 + d], a);
      r[q] = fmaxf(a, 0.f);
    }
    *(f32x4*)(out + (size_t)m * 32 + o) = r;
  }
}

extern "C" void kernel_launch(void* const* d_in, const int* in_sizes, int n_in,
                              void* d_out, int out_size, void* d_ws, size_t ws_size,
                              hipStream_t stream) {
  const float* A = (const float*)d_in[0];
  const float* X = (const float*)d_in[1];
  const float* W = (const float*)d_in[2];
  const float* b = (const float*)d_in[3];
  const void*  keep_raw = (const void*)d_in[4];
  float* out = (float*)d_out;

  const size_t xm_bytes    = (size_t)NSLICES * SLICE_US * 2;       // 2,621,440
  const size_t partz_bytes = (size_t)KSPLIT * N_NODES * 32 * 4;    // 8,388,608
  if (ws_size < MASK_WS + xm_bytes + partz_bytes) return;  // need ~11 MB

  unsigned char* mk = (unsigned char*)d_ws;
  unsigned short* XmG = (unsigned short*)((char*)d_ws + MASK_WS);
  float* partZ = (float*)((char*)d_ws + MASK_WS + xm_bytes);

  prep_kernel<<<dim3(NSLICES), 256, 0, stream>>>(X, keep_raw, mk, XmG);
  gemm_kernel<<<dim3(N_NODES / 256, KSPLIT), 512, 0, stream>>>(A, XmG, mk, partZ);
  epi_kernel<<<dim3(N_NODES / 64), 64, 0, stream>>>(partZ, W, b, out);
}

// Round 8
// 93.483 us; speedup vs baseline: 1.1834x; 1.1834x over previous
//
#include <hip/hip_runtime.h>

// DropGCN: out = relu( mean_r( diag(k_r) A diag(k_r) X ) @ W^T + b )
//  == Y[8192,160] = A @ Xm   (Xm[:, r*32+d] = k_r .* X[:,d], bf16)
//  then per-row masked mean over the 5 replica slices, @W^T, +b, relu.
//
// Round 8: DECOMPOSITION round. gemm + epi are the r4 champion (97.4 us)
// byte-for-byte: 256-row blocks, 8 waves x 2 m-tiles, KSPLIT=8, 2D grid,
// linear XmG + in-gemm swizzled LDS staging, __syncthreads double-buffer.
// ONLY change: prep is the r6-verified coalesced LDS-transpose version
// (writing LINEAR XmG to match r4's gemm), mask-norm merged in. r4's prep
// read X[j*32+d] with j as the lane index -> 128 B line per lane, ~670 MB
// of L2 line traffic (~15 us). This isolates prep's share of the 97.4.

#define N_NODES   8192
#define NSLICES   256          // 8192/32 K-slices
#define NCOLS     160          // 5 replicas * 32 dims
#define SLICE_US  5120         // ushorts per K-slice image (160*32)
#define MASK_WS   65536        // ws bytes reserved for normalized mask
#define KSPLIT    8
#define STEPS     (NSLICES / KSPLIT)   // 32 K-steps per block

typedef __attribute__((ext_vector_type(4))) float f32x4;
typedef __attribute__((ext_vector_type(8))) short bf16x8;

__device__ __forceinline__ unsigned short f2bf(float f) {
  // round-to-nearest-even f32 -> bf16 bits
  unsigned int u = __builtin_bit_cast(unsigned int, f);
  return (unsigned short)((u + 0x7FFFu + ((u >> 16) & 1u)) >> 16);
}

__device__ __forceinline__ unsigned pack_bf(float lo, float hi) {
  // two f32 -> packed bf16 pair (round-to-nearest ties-up; verified r3-r7)
  unsigned u0 = __builtin_bit_cast(unsigned, lo) + 0x8000u;
  unsigned u1 = __builtin_bit_cast(unsigned, hi) + 0x8000u;
  return (u1 & 0xFFFF0000u) | (u0 >> 16);
}

// ---------------------------------------------------------------------------
// prep: block s handles K-slice s (32 nodes x all 160 cols), all coalesced.
//  - read X[s*32..+32)[0..32) as 256 f32x4 -> LDS transposed [kk][d]
//  - mask dtype detect (u8 vs u32/f32 words), normalize -> mk + LDS floats
//  - write XmG[s][n][kk] LINEAR (kg = c&3; matches r4 gemm staging exactly):
//    chunk c (16 B) = (n = c>>2, kg = c&3), elems e: kk = kg*8+e.
// ---------------------------------------------------------------------------
__global__ __launch_bounds__(256) void prep_kernel(
    const float* __restrict__ X, const void* __restrict__ raw,
    unsigned char* __restrict__ mk, unsigned short* __restrict__ XmG) {
  __shared__ float xt[32 * 33];   // [kk][d], pad 33
  __shared__ float mf[160];       // [r][kk] 0/1
  __shared__ int mode32s;
  const int tid = threadIdx.x;
  const int s = blockIdx.x;

  if (tid == 0) {
    const unsigned* wrd = (const unsigned*)raw;
    int ok = 1;
    for (int i = 0; i < 64; ++i) {
      unsigned v = wrd[i];
      if (!(v <= 1u || v == 0x3F800000u)) { ok = 0; break; }
    }
    mode32s = ok;
  }
  f32x4 xv = *(const f32x4*)(X + (size_t)s * 1024 + tid * 4);
  __syncthreads();
  const int mode32 = mode32s;
#pragma unroll
  for (int q = 0; q < 4; ++q) {
    int e = tid * 4 + q;                 // e = jj*32 + d
    xt[(e >> 5) * 33 + (e & 31)] = xv[q];
  }
  if (tid < 160) {
    int r = tid >> 5, jj = tid & 31;
    int gi = r * N_NODES + s * 32 + jj;
    unsigned char kv = mode32 ? (unsigned char)(((const unsigned*)raw)[gi] != 0u)
                              : (unsigned char)(((const unsigned char*)raw)[gi] != 0);
    mk[gi] = kv;
    mf[tid] = kv ? 1.0f : 0.0f;
  }
  __syncthreads();

  unsigned short* outp = XmG + (size_t)s * SLICE_US;
  for (int c = tid; c < 640; c += 256) {
    int n = c >> 2, kg = c & 3;          // LINEAR layout (r4-compatible)
    int r = n >> 5, d = n & 31;
    union { bf16x8 v; unsigned short us[8]; } o;
#pragma unroll
    for (int e = 0; e < 8; ++e) {
      int kk = kg * 8 + e;
      o.us[e] = f2bf(mf[r * 32 + kk] * xt[kk * 33 + d]);
    }
    *(bf16x8*)(outp + c * 8) = o.v;
  }
}

// ---------------------------------------------------------------------------
// gemm (r4 champion, verbatim): block = 8 waves x 32 rows = 256 rows, all
// 160 cols, K-range 1024. LDS double-buffer of one 10 KB K-slice, 1 barrier
// per step, reg-staged with XOR swizzle: slice ushort (n*32+kg*8+e) at LDS
// ushort n*32 + ((kg ^ ((n>>1)&3))*8) + e.
// Verified D map: acc[nt][jj] = Y[base_m + n0][nt*16 + kg*4 + jj].
// Fused replica mask-mean epilogue -> partZ[sy][m][d] f32.
// ---------------------------------------------------------------------------
__global__ __launch_bounds__(512, 2) void gemm_kernel(
    const float* __restrict__ A, const unsigned short* __restrict__ XmG,
    const unsigned char* __restrict__ mk, float* __restrict__ partZ) {
  __shared__ __align__(16) unsigned short xm[2][SLICE_US];   // 20 KB

  const int tid  = threadIdx.x;
  const int lane = tid & 63;
  const int w    = tid >> 6;        // wave 0..7
  const int n0   = lane & 15;
  const int kg   = lane >> 4;       // k-group 0..3 (8 elems each)
  const int sy   = blockIdx.y;      // k-split 0..7
  const int s_base = sy * STEPS;
  const int base_m = blockIdx.x * 256 + w * 32;   // wave owns 32 rows

  // A rows for the wave's two 16-row tiles
  const float* aptr0 =
      A + (size_t)(base_m + n0) * N_NODES + s_base * 32 + kg * 8;
  const float* aptr1 = aptr0 + (size_t)16 * N_NODES;

  // staging: thread stages chunk c0=tid (and c1=tid+512 if tid<128);
  // chunk c = 16 B at slice ushort c*8 -> n = c>>2, kgs = c&3
  const unsigned short* xsrc = XmG + (size_t)s_base * SLICE_US;
  const int c0 = tid, n_c0 = c0 >> 2;
  const int off0 = n_c0 * 32 + (((c0 & 3) ^ ((n_c0 >> 1) & 3)) << 3);
  const int c1 = tid + 512, n_c1 = c1 >> 2;
  const int off1 = n_c1 * 32 + (((c1 & 3) ^ ((n_c1 >> 1) & 3)) << 3);
  const bool has2 = (tid < 128);

  // fragment read base (swizzled slot depends only on n0,kg)
  const unsigned short* frag0 =
      &xm[0][0] + n0 * 32 + ((kg ^ ((n0 >> 1) & 3)) << 3);

  f32x4 acc0[10], acc1[10];
#pragma unroll
  for (int i = 0; i < 10; ++i) {
    acc0[i] = (f32x4){0.f, 0.f, 0.f, 0.f};
    acc1[i] = (f32x4){0.f, 0.f, 0.f, 0.f};
  }

  // prologue: slice 0 -> regs -> LDS buf0; slice 1 -> regs; A step-0 regs
  bf16x8 sa = *(const bf16x8*)(xsrc + c0 * 8);
  bf16x8 sb2 = sa;
  if (has2) sb2 = *(const bf16x8*)(xsrc + c1 * 8);
  f32x4 a0  = __builtin_nontemporal_load((const f32x4*)aptr0);
  f32x4 a0b = __builtin_nontemporal_load((const f32x4*)(aptr0 + 4));
  f32x4 a1  = __builtin_nontemporal_load((const f32x4*)aptr1);
  f32x4 a1b = __builtin_nontemporal_load((const f32x4*)(aptr1 + 4));
  *(bf16x8*)(&xm[0][off0]) = sa;
  if (has2) *(bf16x8*)(&xm[0][off1]) = sb2;
  sa = *(const bf16x8*)(xsrc + SLICE_US + c0 * 8);
  if (has2) sb2 = *(const bf16x8*)(xsrc + SLICE_US + c1 * 8);
  __syncthreads();

  int cur = 0;
  for (int step = 0; step < STEPS; ++step) {
    // stage slice step+1 into the other buffer (its prior readers finished
    // before the barrier that ended step-1)
    if (step + 1 < STEPS) {
      unsigned short* dst = &xm[cur ^ 1][0];
      *(bf16x8*)(dst + off0) = sa;
      if (has2) *(bf16x8*)(dst + off1) = sb2;
    }
    // issue global load of slice step+2 (lands during compute + barrier)
    if (step + 2 < STEPS) {
      const unsigned short* s2 = xsrc + (size_t)(step + 2) * SLICE_US;
      sa = *(const bf16x8*)(s2 + c0 * 8);
      if (has2) sb2 = *(const bf16x8*)(s2 + c1 * 8);
    }
    // prefetch next step's A registers (streaming)
    const int nxt = (step + 1 < STEPS) ? (step + 1) : step;
    f32x4 na0  = __builtin_nontemporal_load((const f32x4*)(aptr0 + (size_t)nxt * 32));
    f32x4 na0b = __builtin_nontemporal_load((const f32x4*)(aptr0 + (size_t)nxt * 32 + 4));
    f32x4 na1  = __builtin_nontemporal_load((const f32x4*)(aptr1 + (size_t)nxt * 32));
    f32x4 na1b = __builtin_nontemporal_load((const f32x4*)(aptr1 + (size_t)nxt * 32 + 4));

    // pack B fragments (same lane->k map as A-op; permutation cancels)
    union { bf16x8 v; unsigned u[4]; } b0, b1;
    b0.u[0] = pack_bf(a0[0], a0[1]);   b0.u[1] = pack_bf(a0[2], a0[3]);
    b0.u[2] = pack_bf(a0b[0], a0b[1]); b0.u[3] = pack_bf(a0b[2], a0b[3]);
    b1.u[0] = pack_bf(a1[0], a1[1]);   b1.u[1] = pack_bf(a1[2], a1[3]);
    b1.u[2] = pack_bf(a1b[0], a1b[1]); b1.u[3] = pack_bf(a1b[2], a1b[3]);

    const unsigned short* fb = frag0 + cur * SLICE_US;
#pragma unroll
    for (int nt = 0; nt < 10; ++nt) {
      bf16x8 af = *(const bf16x8*)(fb + nt * 512);
      acc0[nt] = __builtin_amdgcn_mfma_f32_16x16x32_bf16(af, b0.v, acc0[nt], 0, 0, 0);
      acc1[nt] = __builtin_amdgcn_mfma_f32_16x16x32_bf16(af, b1.v, acc1[nt], 0, 0, 0);
    }
    __syncthreads();   // reads of buf[cur] done; buf[cur^1] writes visible
    cur ^= 1;
    a0 = na0; a0b = na0b; a1 = na1; a1b = na1b;
  }

  // fused replica mask-mean epilogue:
  // acc[2t][jj]  = Y[m][32t + kg*4+jj]       (d = kg*4+jj,    r = t)
  // acc[2t+1][jj]= Y[m][32t + 16 + kg*4+jj]  (d = kg*4+jj+16, r = t)
  const int m0g = base_m + n0;
  const int m1g = m0g + 16;
  float w0[5], w1[5];
#pragma unroll
  for (int t = 0; t < 5; ++t) {
    w0[t] = mk[t * N_NODES + m0g] ? 0.2f : 0.0f;
    w1[t] = mk[t * N_NODES + m1g] ? 0.2f : 0.0f;
  }
  f32x4 zA0 = (f32x4){0.f, 0.f, 0.f, 0.f}, zB0 = zA0, zA1 = zA0, zB1 = zA0;
#pragma unroll
  for (int t = 0; t < 5; ++t) {
    zA0 += w0[t] * acc0[2 * t];
    zB0 += w0[t] * acc0[2 * t + 1];
    zA1 += w1[t] * acc1[2 * t];
    zB1 += w1[t] * acc1[2 * t + 1];
  }
  float* p0 = partZ + ((size_t)sy * N_NODES + m0g) * 32 + kg * 4;
  *(f32x4*)(p0)      = zA0;
  *(f32x4*)(p0 + 16) = zB0;
  float* p1 = partZ + ((size_t)sy * N_NODES + m1g) * 32 + kg * 4;
  *(f32x4*)(p1)      = zA1;
  *(f32x4*)(p1 + 16) = zB1;
}

// ---------------------------------------------------------------------------
// epi: z[m][d] = sum_s partZ[s][m][d];  out[m][o] = relu(b[o] + z . W[o])
// ---------------------------------------------------------------------------
__global__ __launch_bounds__(64) void epi_kernel(
    const float* __restrict__ partZ, const float* __restrict__ W,
    const float* __restrict__ bias, float* __restrict__ out) {
  __shared__ float sW[1024];
  __shared__ float sb[32];
  const int tid = threadIdx.x;
  for (int i = tid; i < 1024; i += 64) sW[i] = W[i];
  if (tid < 32) sb[tid] = bias[tid];
  __syncthreads();

  const int m = blockIdx.x * 64 + tid;
  float zz[32];
#pragma unroll
  for (int i = 0; i < 32; ++i) zz[i] = 0.f;
  const float* p = partZ + (size_t)m * 32;
  for (int s = 0; s < KSPLIT; ++s) {
    const float* ps = p + (size_t)s * N_NODES * 32;
#pragma unroll
    for (int i = 0; i < 8; ++i) {
      f32x4 v = *(const f32x4*)(ps + i * 4);
      zz[4 * i + 0] += v[0]; zz[4 * i + 1] += v[1];
      zz[4 * i + 2] += v[2]; zz[4 * i + 3] += v[3];
    }
  }
#pragma unroll
  for (int o = 0; o < 32; o += 4) {
    f32x4 r;
#pragma unroll
    for (int q = 0; q < 4; ++q) {
      float a = sb[o + q];
#pragma unroll
      for (int d = 0; d < 32; ++d) a = fmaf(zz[d], sW[(o + q) * 32 + d], a);
      r[q] = fmaxf(a, 0.f);
    }
    *(f32x4*)(out + (size_t)m * 32 + o) = r;
  }
}

extern "C" void kernel_launch(void* const* d_in, const int* in_sizes, int n_in,
                              void* d_out, int out_size, void* d_ws, size_t ws_size,
                              hipStream_t stream) {
  const float* A = (const float*)d_in[0];
  const float* X = (const float*)d_in[1];
  const float* W = (const float*)d_in[2];
  const float* b = (const float*)d_in[3];
  const void*  keep_raw = (const void*)d_in[4];
  float* out = (float*)d_out;

  const size_t xm_bytes    = (size_t)NSLICES * SLICE_US * 2;       // 2,621,440
  const size_t partz_bytes = (size_t)KSPLIT * N_NODES * 32 * 4;    // 8,388,608
  if (ws_size < MASK_WS + xm_bytes + partz_bytes) return;  // need ~11 MB

  unsigned char* mk = (unsigned char*)d_ws;
  unsigned short* XmG = (unsigned short*)((char*)d_ws + MASK_WS);
  float* partZ = (float*)((char*)d_ws + MASK_WS + xm_bytes);

  prep_kernel<<<dim3(NSLICES), 256, 0, stream>>>(X, keep_raw, mk, XmG);
  gemm_kernel<<<dim3(N_NODES / 256, KSPLIT), 512, 0, stream>>>(A, XmG, mk, partZ);
  epi_kernel<<<dim3(N_NODES / 64), 64, 0, stream>>>(partZ, W, b, out);
}